// Round 36
// baseline (152.249 us; speedup 1.0000x reference)
//
#include <hip/hip_runtime.h>
#include <hip/hip_bf16.h>

#define BN 2048      // B*N
#define NSEQ 512
#define D 256
#define H 128
#define R 16
#define AC 5
#define CHUNK 128
#define ROWG 8
#define SPLIT 4
#define NPERS 2048   // persistent blocks (= 8/CU * 256 CU thread capacity)

using bf16 = __hip_bfloat16;

__device__ __forceinline__ float fast_silu(float t) {
    const float e = __expf(-t);
    return t * __builtin_amdgcn_rcpf(1.0f + e);
}
__device__ __forceinline__ float bf2f(unsigned short u) {
    return __uint_as_float(((unsigned)u) << 16);
}
__device__ __forceinline__ unsigned short f2bu(float v) {
    const bf16 pb = __float2bfloat16(v);
    return *(const unsigned short*)&pb;
}

// ---------------- Kernel 0: per-batch valid-j compaction + coord sum + counter reset ----------------
__global__ __launch_bounds__(256) void batch_kernel(
    const int* __restrict__ pad, const float* __restrict__ coords,
    int* __restrict__ jlist_g, int* __restrict__ M_g, float* __restrict__ csum_g,
    int* __restrict__ counter)
{
    const int b = blockIdx.x;
    const int tid = threadIdx.x;
    if (b == 0 && tid == 0) counter[0] = 0;   // work-stealing counter reset (stream-ordered)
    __shared__ int s_wcnt[8];
    __shared__ int s_wbase[8];
    __shared__ float r1[256], r2[256], r3[256];
    const int wv = tid >> 6, lane = tid & 63;
    unsigned long long bm[2];
    float sx = 0.0f, sy = 0.0f, sz = 0.0f;
    #pragma unroll
    for (int cc = 0; cc < 2; ++cc) {
        const int j = cc * 256 + tid;
        const int ok = (pad[b * NSEQ + j] == 0);
        bm[cc] = __ballot(ok);
        if (lane == 0) s_wcnt[cc * 4 + wv] = __popcll(bm[cc]);
        if (ok) {
            sx += coords[(size_t)(b * NSEQ + j) * 3 + 0];
            sy += coords[(size_t)(b * NSEQ + j) * 3 + 1];
            sz += coords[(size_t)(b * NSEQ + j) * 3 + 2];
        }
    }
    r1[tid] = sx; r2[tid] = sy; r3[tid] = sz;
    __syncthreads();
    for (int s = 128; s > 0; s >>= 1) {
        if (tid < s) { r1[tid] += r1[tid + s]; r2[tid] += r2[tid + s]; r3[tid] += r3[tid + s]; }
        __syncthreads();
    }
    if (tid == 0) {
        int acc = 0;
        #pragma unroll
        for (int q = 0; q < 8; ++q) { s_wbase[q] = acc; acc += s_wcnt[q]; }
        M_g[b] = acc;
        csum_g[b * 3 + 0] = r1[0];
        csum_g[b * 3 + 1] = r2[0];
        csum_g[b * 3 + 2] = r3[0];
    }
    __syncthreads();
    #pragma unroll
    for (int cc = 0; cc < 2; ++cc) {
        const int j = cc * 256 + tid;
        if (pad[b * NSEQ + j] == 0) {
            const int pos = s_wbase[cc * 4 + wv]
                          + __popcll(bm[cc] & ((1ull << lane) - 1ull));
            jlist_g[b * NSEQ + pos] = j;
        }
    }
}

// ---------------- Kernel 1: atom head + pj(bf16) + pib(bf16), ROWG=8, 512 threads (R35, passes) ----------------
__global__ __launch_bounds__(512) void row_kernel(
    const float* __restrict__ trunk, const int* __restrict__ pad,
    const float* __restrict__ ln_g, const float* __restrict__ ln_b,
    const float* __restrict__ w_a1, const float* __restrict__ b_a1,
    const float* __restrict__ w_a2, const float* __restrict__ b_a2,
    const float* __restrict__ w_pi, const float* __restrict__ w_pj,
    const float* __restrict__ b_p1,
    float* __restrict__ out_atom, unsigned short* __restrict__ pj_o,
    unsigned short* __restrict__ pib_o)
{
    const int row0 = blockIdx.x * ROWG;
    const int tid = threadIdx.x;   // 0..511
    const int wv = tid >> 6, lane = tid & 63;
    __shared__ __align__(16) float x_t[2][D][4];
    __shared__ __align__(16) float xn_t[2][D][4];
    __shared__ float y[ROWG][D];
    __shared__ float mu_s[ROWG], rs_s[ROWG];

    #pragma unroll
    for (int gg = 0; gg < 4; ++gg) {
        const int g = gg * 2 + (tid >> 8);
        const int e = tid & 255;
        x_t[g >> 2][e][g & 3] = trunk[(size_t)(row0 + g) * D + e];
    }
    __syncthreads();

    {
        const int g = wv;
        float s = 0.0f, ss = 0.0f;
        #pragma unroll
        for (int e2 = lane; e2 < D; e2 += 64) {
            const float v = x_t[g >> 2][e2][g & 3];
            s += v; ss += v * v;
        }
        #pragma unroll
        for (int off = 32; off; off >>= 1) {
            s  += __shfl_xor(s, off);
            ss += __shfl_xor(ss, off);
        }
        if (lane == 0) {
            const float mu  = s * (1.0f / D);
            const float var = ss * (1.0f / D) - mu * mu;
            mu_s[g] = mu;
            rs_s[g] = rsqrtf(var + 1e-5f);
        }
    }
    __syncthreads();
    #pragma unroll
    for (int gg = 0; gg < 4; ++gg) {
        const int g = gg * 2 + (tid >> 8);
        const int e = tid & 255;
        xn_t[g >> 2][e][g & 3] =
            (x_t[g >> 2][e][g & 3] - mu_s[g]) * rs_s[g] * ln_g[e] + ln_b[e];
    }
    __syncthreads();

    if (tid < 256) {
        const float bb = b_a1[tid];
        float a0 = bb, a1v = bb, a2v = bb, a3 = bb, a4 = bb, a5 = bb, a6 = bb, a7 = bb;
        for (int d = 0; d < D; ++d) {
            const float w = w_a1[d * D + tid];
            const float4 lo = *(const float4*)xn_t[0][d];
            const float4 hi = *(const float4*)xn_t[1][d];
            a0  = fmaf(lo.x, w, a0);  a1v = fmaf(lo.y, w, a1v);
            a2v = fmaf(lo.z, w, a2v); a3  = fmaf(lo.w, w, a3);
            a4  = fmaf(hi.x, w, a4);  a5  = fmaf(hi.y, w, a5);
            a6  = fmaf(hi.z, w, a6);  a7  = fmaf(hi.w, w, a7);
        }
        y[0][tid] = a0  / (1.0f + expf(-a0));
        y[1][tid] = a1v / (1.0f + expf(-a1v));
        y[2][tid] = a2v / (1.0f + expf(-a2v));
        y[3][tid] = a3  / (1.0f + expf(-a3));
        y[4][tid] = a4  / (1.0f + expf(-a4));
        y[5][tid] = a5  / (1.0f + expf(-a5));
        y[6][tid] = a6  / (1.0f + expf(-a6));
        y[7][tid] = a7  / (1.0f + expf(-a7));
    } else if (tid < 384) {
        const int h = tid - 256;
        float p0 = 0.f, p1 = 0.f, p2 = 0.f, p3 = 0.f, p4 = 0.f, p5 = 0.f, p6 = 0.f, p7 = 0.f;
        for (int d = 0; d < D; ++d) {
            const float w = w_pi[d * H + h];
            const float4 lo = *(const float4*)x_t[0][d];
            const float4 hi = *(const float4*)x_t[1][d];
            p0 = fmaf(lo.x, w, p0); p1 = fmaf(lo.y, w, p1);
            p2 = fmaf(lo.z, w, p2); p3 = fmaf(lo.w, w, p3);
            p4 = fmaf(hi.x, w, p4); p5 = fmaf(hi.y, w, p5);
            p6 = fmaf(hi.z, w, p6); p7 = fmaf(hi.w, w, p7);
        }
        const float bb = b_p1[h];
        const float pv[ROWG] = {p0 + bb, p1 + bb, p2 + bb, p3 + bb,
                                p4 + bb, p5 + bb, p6 + bb, p7 + bb};
        #pragma unroll
        for (int g = 0; g < ROWG; ++g)
            pib_o[(size_t)(row0 + g) * H + h] = f2bu(pv[g]);
    } else {
        const int h = tid - 384;
        float p0 = 0.f, p1 = 0.f, p2 = 0.f, p3 = 0.f, p4 = 0.f, p5 = 0.f, p6 = 0.f, p7 = 0.f;
        for (int d = 0; d < D; ++d) {
            const float w = w_pj[d * H + h];
            const float4 lo = *(const float4*)x_t[0][d];
            const float4 hi = *(const float4*)x_t[1][d];
            p0 = fmaf(lo.x, w, p0); p1 = fmaf(lo.y, w, p1);
            p2 = fmaf(lo.z, w, p2); p3 = fmaf(lo.w, w, p3);
            p4 = fmaf(hi.x, w, p4); p5 = fmaf(hi.y, w, p5);
            p6 = fmaf(hi.z, w, p6); p7 = fmaf(hi.w, w, p7);
        }
        const float pv[ROWG] = {p0, p1, p2, p3, p4, p5, p6, p7};
        #pragma unroll
        for (int g = 0; g < ROWG; ++g)
            pj_o[(size_t)(row0 + g) * H + h] = f2bu(pv[g]);
    }
    __syncthreads();

    if (tid < ROWG * AC) {
        const int g = tid / AC, c = tid % AC;
        float a = b_a2[c];
        for (int d = 0; d < D; ++d) a = fmaf(y[g][d], w_a2[d * AC + c], a);
        out_atom[(row0 + g) * AC + c] = (pad[row0 + g] != 0) ? 0.0f : a;
    }
}

// per-pair inner body (R35, passes)
__device__ __forceinline__ void pair_body(
    const float pvx, const float pvy,
    const float* __restrict__ rbf_row, const float4 dk,
    const float pibx, const float piby,
    const float* wprA, const float* wprB, const float2 wp22,
    float& cdx, float& cdy, float& cdz)
{
    float t0a = pibx + pvx, t0b = 0.0f;
    float t1a = piby + pvy, t1b = 0.0f;
    #pragma unroll
    for (int r = 0; r < R; r += 2) {
        const float qa = rbf_row[r];
        const float qb = rbf_row[r + 1];
        t0a = fmaf(qa, wprA[r],     t0a);
        t0b = fmaf(qb, wprA[r + 1], t0b);
        t1a = fmaf(qa, wprB[r],     t1a);
        t1b = fmaf(qb, wprB[r + 1], t1b);
    }
    const float u0 = fast_silu(t0a + t0b);
    const float u1 = fast_silu(t1a + t1b);
    const float part = u0 * wp22.x + u1 * wp22.y;
    cdx = fmaf(part, dk.x, cdx);
    cdy = fmaf(part, dk.y, cdy);
    cdz = fmaf(part, dk.z, cdz);
}

// ---------------- Kernel 2: pair head — PERSISTENT blocks, atomic work stealing ----------------
__global__ __launch_bounds__(256) void pair_kernel(
    const float* __restrict__ coords, const int* __restrict__ pad,
    const float* __restrict__ w_pr, const float* __restrict__ w_p2,
    const unsigned short* __restrict__ pj_i, const unsigned short* __restrict__ pib_i,
    const int* __restrict__ jlist_g, const int* __restrict__ M_g,
    int* __restrict__ counter,
    float* __restrict__ cd_part)   // [BN][SPLIT][3]
{
    const int tid = threadIdx.x;
    const int wv = tid >> 6, lane = tid & 63;

    __shared__ __align__(16) float s_rbf[CHUNK][20];
    __shared__ __align__(16) float4 s_d4[CHUNK];
    __shared__ int   s_jl[CHUNK];
    __shared__ float rw1[4], rw2[4], rw3[4];
    __shared__ int   s_item;

    // block-constant state (amortized over all grabbed items)
    float wprA[R], wprB[R];
    #pragma unroll
    for (int r = 0; r < R; ++r) {
        const float2 wv2 = ((const float2*)(w_pr + r * H))[lane];
        wprA[r] = wv2.x;
        wprB[r] = wv2.y;
    }
    const float2 wp22 = ((const float2*)w_p2)[lane];
    const float gamma = 14.0625f;  // (15/4)^2

    for (;;) {
        __syncthreads();                       // protect s_item reuse
        if (tid == 0) s_item = atomicAdd(counter, 1);
        __syncthreads();
        const int item = s_item;
        if (item >= BN * SPLIT) break;         // block-uniform exit

        const int row = item >> 2;
        const int part_id = item & 3;
        const int b = row >> 9;

        if (pad[row] != 0) {
            if (tid == 0) {
                cd_part[(row * SPLIT + part_id) * 3 + 0] = 0.0f;
                cd_part[(row * SPLIT + part_id) * 3 + 1] = 0.0f;
                cd_part[(row * SPLIT + part_id) * 3 + 2] = 0.0f;
            }
            continue;
        }

        const int M = M_g[b];
        const int Mq  = (M + SPLIT - 1) / SPLIT;
        const int kLo = part_id * Mq;
        const int kHi = min(M, kLo + Mq);

        const ushort2 pibu = ((const ushort2*)(pib_i + (size_t)row * H))[lane];
        const float pibx = bf2f(pibu.x), piby = bf2f(pibu.y);
        const float cix = coords[(size_t)row * 3 + 0];
        const float ciy = coords[(size_t)row * 3 + 1];
        const float ciz = coords[(size_t)row * 3 + 2];
        const unsigned short* pjb = pj_i + (size_t)b * NSEQ * H;

        float cdx = 0.0f, cdy = 0.0f, cdz = 0.0f;

        for (int c0 = kLo; c0 < kHi; c0 += CHUNK) {
            const int cn = (kHi - c0 < CHUNK) ? (kHi - c0) : CHUNK;
            __syncthreads();
            if (tid < cn) {
                const int j = jlist_g[b * NSEQ + c0 + tid];
                s_jl[tid] = j;
                const float* cj = coords + (size_t)(b * NSEQ + j) * 3;
                const float dx = cix - cj[0];
                const float dy = ciy - cj[1];
                const float dz = ciz - cj[2];
                const float sq = dx * dx + dy * dy + dz * dz;
                const float dist = sqrtf(fmaxf(sq, 1e-12f));
                s_d4[tid] = make_float4(dx, dy, dz, 0.0f);
                #pragma unroll
                for (int c = 0; c < 4; ++c) {
                    float4 q;
                    const float t0 = dist - (float)(4.0 * (4 * c + 0) / 15.0);
                    const float t1 = dist - (float)(4.0 * (4 * c + 1) / 15.0);
                    const float t2 = dist - (float)(4.0 * (4 * c + 2) / 15.0);
                    const float t3 = dist - (float)(4.0 * (4 * c + 3) / 15.0);
                    q.x = __expf(-gamma * t0 * t0);
                    q.y = __expf(-gamma * t1 * t1);
                    q.z = __expf(-gamma * t2 * t2);
                    q.w = __expf(-gamma * t3 * t3);
                    *(float4*)(&s_rbf[tid][4 * c]) = q;
                }
            }
            __syncthreads();

            const int cl = cn - 1;
            int k = wv;
            ushort2 pv0 = ((const ushort2*)(pjb + (size_t)s_jl[min(k,      cl)] * H))[lane];
            ushort2 pv1 = ((const ushort2*)(pjb + (size_t)s_jl[min(k + 4,  cl)] * H))[lane];
            ushort2 pv2 = ((const ushort2*)(pjb + (size_t)s_jl[min(k + 8,  cl)] * H))[lane];
            ushort2 pv3 = ((const ushort2*)(pjb + (size_t)s_jl[min(k + 12, cl)] * H))[lane];
            for (; k < cn; k += 16) {
                const int kn = k + 16;
                const ushort2 nv0 = ((const ushort2*)(pjb + (size_t)s_jl[min(kn,      cl)] * H))[lane];
                const ushort2 nv1 = ((const ushort2*)(pjb + (size_t)s_jl[min(kn + 4,  cl)] * H))[lane];
                const ushort2 nv2 = ((const ushort2*)(pjb + (size_t)s_jl[min(kn + 8,  cl)] * H))[lane];
                const ushort2 nv3 = ((const ushort2*)(pjb + (size_t)s_jl[min(kn + 12, cl)] * H))[lane];

                const int k1 = k + 4, k2 = k + 8, k3 = k + 12;
                pair_body(bf2f(pv0.x), bf2f(pv0.y), s_rbf[k], s_d4[k], pibx, piby,
                          wprA, wprB, wp22, cdx, cdy, cdz);
                if (k1 < cn) pair_body(bf2f(pv1.x), bf2f(pv1.y), s_rbf[k1], s_d4[k1], pibx, piby,
                                       wprA, wprB, wp22, cdx, cdy, cdz);
                if (k2 < cn) pair_body(bf2f(pv2.x), bf2f(pv2.y), s_rbf[k2], s_d4[k2], pibx, piby,
                                       wprA, wprB, wp22, cdx, cdy, cdz);
                if (k3 < cn) pair_body(bf2f(pv3.x), bf2f(pv3.y), s_rbf[k3], s_d4[k3], pibx, piby,
                                       wprA, wprB, wp22, cdx, cdy, cdz);
                pv0 = nv0; pv1 = nv1; pv2 = nv2; pv3 = nv3;
            }
        }
        #pragma unroll
        for (int off = 32; off; off >>= 1) {
            cdx += __shfl_xor(cdx, off);
            cdy += __shfl_xor(cdy, off);
            cdz += __shfl_xor(cdz, off);
        }
        if (lane == 0) { rw1[wv] = cdx; rw2[wv] = cdy; rw3[wv] = cdz; }
        __syncthreads();
        if (tid == 0) {
            cd_part[(row * SPLIT + part_id) * 3 + 0] = rw1[0] + rw1[1] + rw1[2] + rw1[3];
            cd_part[(row * SPLIT + part_id) * 3 + 1] = rw2[0] + rw2[1] + rw2[2] + rw2[3];
            cd_part[(row * SPLIT + part_id) * 3 + 2] = rw3[0] + rw3[1] + rw3[2] + rw3[3];
        }
    }
}

// ---------------- Kernel 3: finalize — closed-form bp2 term, CoM, /denom (R35, passes) ----------------
__global__ __launch_bounds__(256) void finalize_kernel(
    const float* __restrict__ cd_part, const int* __restrict__ pad,
    const float* __restrict__ coords, const int* __restrict__ M_g,
    const float* __restrict__ csum_g, const float* __restrict__ b_p2,
    float* __restrict__ out_coord)
{
    const int b = blockIdx.x;
    const int tid = threadIdx.x;
    __shared__ float r1[256], r2[256], r3[256];
    const float bp2 = b_p2[0];
    const float Mf  = (float)M_g[b];
    const float csx = csum_g[b * 3 + 0];
    const float csy = csum_g[b * 3 + 1];
    const float csz = csum_g[b * 3 + 2];

    float sx = 0.0f, sy = 0.0f, sz = 0.0f;
    for (int ii = tid; ii < NSEQ; ii += 256) {
        const int row = b * NSEQ + ii;
        if (pad[row] == 0) {
            float cx = bp2 * fmaf(Mf, coords[(size_t)row * 3 + 0], -csx);
            float cy = bp2 * fmaf(Mf, coords[(size_t)row * 3 + 1], -csy);
            float cz = bp2 * fmaf(Mf, coords[(size_t)row * 3 + 2], -csz);
            #pragma unroll
            for (int q = 0; q < SPLIT; ++q) {
                cx += cd_part[(row * SPLIT + q) * 3 + 0];
                cy += cd_part[(row * SPLIT + q) * 3 + 1];
                cz += cd_part[(row * SPLIT + q) * 3 + 2];
            }
            sx += cx; sy += cy; sz += cz;
        }
    }
    r1[tid] = sx; r2[tid] = sy; r3[tid] = sz;
    __syncthreads();
    for (int s = 128; s > 0; s >>= 1) {
        if (tid < s) { r1[tid] += r1[tid + s]; r2[tid] += r2[tid + s]; r3[tid] += r3[tid + s]; }
        __syncthreads();
    }
    const float denom = fmaxf(Mf, 1.0f);
    const float inv_d = 1.0f / denom;
    const float mx = r1[0] * inv_d * inv_d;
    const float my = r2[0] * inv_d * inv_d;
    const float mz = r3[0] * inv_d * inv_d;
    for (int ii = tid; ii < NSEQ; ii += 256) {
        const int row = b * NSEQ + ii;
        if (pad[row] == 0) {
            float cx = bp2 * fmaf(Mf, coords[(size_t)row * 3 + 0], -csx);
            float cy = bp2 * fmaf(Mf, coords[(size_t)row * 3 + 1], -csy);
            float cz = bp2 * fmaf(Mf, coords[(size_t)row * 3 + 2], -csz);
            #pragma unroll
            for (int q = 0; q < SPLIT; ++q) {
                cx += cd_part[(row * SPLIT + q) * 3 + 0];
                cy += cd_part[(row * SPLIT + q) * 3 + 1];
                cz += cd_part[(row * SPLIT + q) * 3 + 2];
            }
            out_coord[row * 3 + 0] = cx * inv_d - mx;
            out_coord[row * 3 + 1] = cy * inv_d - my;
            out_coord[row * 3 + 2] = cz * inv_d - mz;
        } else {
            out_coord[row * 3 + 0] = 0.0f;
            out_coord[row * 3 + 1] = 0.0f;
            out_coord[row * 3 + 2] = 0.0f;
        }
    }
}

extern "C" void kernel_launch(void* const* d_in, const int* in_sizes, int n_in,
                              void* d_out, int out_size, void* d_ws, size_t ws_size,
                              hipStream_t stream) {
    const float* trunk  = (const float*)d_in[0];
    const float* coords = (const float*)d_in[1];
    const int*   pad    = (const int*)d_in[2];
    const float* ln_g   = (const float*)d_in[3];
    const float* ln_b   = (const float*)d_in[4];
    const float* w_a1   = (const float*)d_in[5];
    const float* b_a1   = (const float*)d_in[6];
    const float* w_a2   = (const float*)d_in[7];
    const float* b_a2   = (const float*)d_in[8];
    const float* w_pi   = (const float*)d_in[9];
    const float* w_pj   = (const float*)d_in[10];
    const float* w_pr   = (const float*)d_in[11];
    const float* b_p1   = (const float*)d_in[12];
    const float* w_p2   = (const float*)d_in[13];
    const float* b_p2   = (const float*)d_in[14];

    float* out_atom  = (float*)d_out;                 // f32 [0:10240]
    float* out_coord = out_atom + (size_t)BN * AC;    // f32 [10240:16384]

    // ws: jlist[4*512] M[16] csum[16] counter[16] | cd_part[BN*SPLIT*3] | pj bf16 | pib bf16
    int*   jlist_g = (int*)d_ws;
    int*   M_g     = jlist_g + 4 * NSEQ;
    float* csum_g  = (float*)(M_g + 16);
    int*   counter = (int*)(csum_g + 16);
    float* cd_part = (float*)(counter + 16);
    unsigned short* pj_buf  = (unsigned short*)(cd_part + (size_t)BN * SPLIT * 3);
    unsigned short* pib_buf = pj_buf + (size_t)BN * H;

    batch_kernel<<<4, 256, 0, stream>>>(pad, coords, jlist_g, M_g, csum_g, counter);
    row_kernel<<<BN / ROWG, 512, 0, stream>>>(trunk, pad, ln_g, ln_b, w_a1, b_a1,
                                              w_a2, b_a2, w_pi, w_pj, b_p1,
                                              out_atom, pj_buf, pib_buf);
    pair_kernel<<<NPERS, 256, 0, stream>>>(coords, pad, w_pr, w_p2,
                                           pj_buf, pib_buf, jlist_g, M_g,
                                           counter, cd_part);
    finalize_kernel<<<4, 256, 0, stream>>>(cd_part, pad, coords, M_g, csum_g,
                                           b_p2, out_coord);
}

// Round 37
// 66.660 us; speedup vs baseline: 2.2840x; 2.2840x over previous
//
#include <hip/hip_runtime.h>
#include <hip/hip_bf16.h>

#define BN 2048      // B*N
#define NSEQ 512
#define D 256
#define H 128
#define R 16
#define AC 5
#define CHUNK 128
#define ROWG 8
#define SPLIT 4

using bf16 = __hip_bfloat16;

__device__ __forceinline__ float fast_silu(float t) {
    const float e = __expf(-t);
    return t * __builtin_amdgcn_rcpf(1.0f + e);
}
__device__ __forceinline__ float bf2f(unsigned short u) {
    return __uint_as_float(((unsigned)u) << 16);
}
__device__ __forceinline__ unsigned short f2bu(float v) {
    const bf16 pb = __float2bfloat16(v);
    return *(const unsigned short*)&pb;
}

// ---------------- Kernel 0: per-batch valid-j compaction + coord sum ----------------
__global__ __launch_bounds__(256) void batch_kernel(
    const int* __restrict__ pad, const float* __restrict__ coords,
    int* __restrict__ jlist_g, int* __restrict__ M_g, float* __restrict__ csum_g)
{
    const int b = blockIdx.x;
    const int tid = threadIdx.x;
    __shared__ int s_wcnt[8];
    __shared__ int s_wbase[8];
    __shared__ float r1[256], r2[256], r3[256];
    const int wv = tid >> 6, lane = tid & 63;
    unsigned long long bm[2];
    float sx = 0.0f, sy = 0.0f, sz = 0.0f;
    #pragma unroll
    for (int cc = 0; cc < 2; ++cc) {
        const int j = cc * 256 + tid;
        const int ok = (pad[b * NSEQ + j] == 0);
        bm[cc] = __ballot(ok);
        if (lane == 0) s_wcnt[cc * 4 + wv] = __popcll(bm[cc]);
        if (ok) {
            sx += coords[(size_t)(b * NSEQ + j) * 3 + 0];
            sy += coords[(size_t)(b * NSEQ + j) * 3 + 1];
            sz += coords[(size_t)(b * NSEQ + j) * 3 + 2];
        }
    }
    r1[tid] = sx; r2[tid] = sy; r3[tid] = sz;
    __syncthreads();
    for (int s = 128; s > 0; s >>= 1) {
        if (tid < s) { r1[tid] += r1[tid + s]; r2[tid] += r2[tid + s]; r3[tid] += r3[tid + s]; }
        __syncthreads();
    }
    if (tid == 0) {
        int acc = 0;
        #pragma unroll
        for (int q = 0; q < 8; ++q) { s_wbase[q] = acc; acc += s_wcnt[q]; }
        M_g[b] = acc;
        csum_g[b * 3 + 0] = r1[0];
        csum_g[b * 3 + 1] = r2[0];
        csum_g[b * 3 + 2] = r3[0];
    }
    __syncthreads();
    #pragma unroll
    for (int cc = 0; cc < 2; ++cc) {
        const int j = cc * 256 + tid;
        if (pad[b * NSEQ + j] == 0) {
            const int pos = s_wbase[cc * 4 + wv]
                          + __popcll(bm[cc] & ((1ull << lane) - 1ull));
            jlist_g[b * NSEQ + pos] = j;
        }
    }
}

// ---------------- Kernel 1: atom head + pj(bf16) + pib(bf16), ROWG=8, 512 threads ----------------
__global__ __launch_bounds__(512) void row_kernel(
    const float* __restrict__ trunk, const int* __restrict__ pad,
    const float* __restrict__ ln_g, const float* __restrict__ ln_b,
    const float* __restrict__ w_a1, const float* __restrict__ b_a1,
    const float* __restrict__ w_a2, const float* __restrict__ b_a2,
    const float* __restrict__ w_pi, const float* __restrict__ w_pj,
    const float* __restrict__ b_p1,
    float* __restrict__ out_atom, unsigned short* __restrict__ pj_o,
    unsigned short* __restrict__ pib_o)
{
    const int row0 = blockIdx.x * ROWG;
    const int tid = threadIdx.x;   // 0..511
    const int wv = tid >> 6, lane = tid & 63;
    __shared__ __align__(16) float x_t[2][D][4];
    __shared__ __align__(16) float xn_t[2][D][4];
    __shared__ float y[ROWG][D];
    __shared__ float mu_s[ROWG], rs_s[ROWG];

    #pragma unroll
    for (int gg = 0; gg < 4; ++gg) {
        const int g = gg * 2 + (tid >> 8);
        const int e = tid & 255;
        x_t[g >> 2][e][g & 3] = trunk[(size_t)(row0 + g) * D + e];
    }
    __syncthreads();

    {
        const int g = wv;
        float s = 0.0f, ss = 0.0f;
        #pragma unroll
        for (int e2 = lane; e2 < D; e2 += 64) {
            const float v = x_t[g >> 2][e2][g & 3];
            s += v; ss += v * v;
        }
        #pragma unroll
        for (int off = 32; off; off >>= 1) {
            s  += __shfl_xor(s, off);
            ss += __shfl_xor(ss, off);
        }
        if (lane == 0) {
            const float mu  = s * (1.0f / D);
            const float var = ss * (1.0f / D) - mu * mu;
            mu_s[g] = mu;
            rs_s[g] = rsqrtf(var + 1e-5f);
        }
    }
    __syncthreads();
    #pragma unroll
    for (int gg = 0; gg < 4; ++gg) {
        const int g = gg * 2 + (tid >> 8);
        const int e = tid & 255;
        xn_t[g >> 2][e][g & 3] =
            (x_t[g >> 2][e][g & 3] - mu_s[g]) * rs_s[g] * ln_g[e] + ln_b[e];
    }
    __syncthreads();

    if (tid < 256) {
        const float bb = b_a1[tid];
        float a0 = bb, a1v = bb, a2v = bb, a3 = bb, a4 = bb, a5 = bb, a6 = bb, a7 = bb;
        for (int d = 0; d < D; ++d) {
            const float w = w_a1[d * D + tid];
            const float4 lo = *(const float4*)xn_t[0][d];
            const float4 hi = *(const float4*)xn_t[1][d];
            a0  = fmaf(lo.x, w, a0);  a1v = fmaf(lo.y, w, a1v);
            a2v = fmaf(lo.z, w, a2v); a3  = fmaf(lo.w, w, a3);
            a4  = fmaf(hi.x, w, a4);  a5  = fmaf(hi.y, w, a5);
            a6  = fmaf(hi.z, w, a6);  a7  = fmaf(hi.w, w, a7);
        }
        y[0][tid] = a0  / (1.0f + expf(-a0));
        y[1][tid] = a1v / (1.0f + expf(-a1v));
        y[2][tid] = a2v / (1.0f + expf(-a2v));
        y[3][tid] = a3  / (1.0f + expf(-a3));
        y[4][tid] = a4  / (1.0f + expf(-a4));
        y[5][tid] = a5  / (1.0f + expf(-a5));
        y[6][tid] = a6  / (1.0f + expf(-a6));
        y[7][tid] = a7  / (1.0f + expf(-a7));
    } else if (tid < 384) {
        const int h = tid - 256;
        float p0 = 0.f, p1 = 0.f, p2 = 0.f, p3 = 0.f, p4 = 0.f, p5 = 0.f, p6 = 0.f, p7 = 0.f;
        for (int d = 0; d < D; ++d) {
            const float w = w_pi[d * H + h];
            const float4 lo = *(const float4*)x_t[0][d];
            const float4 hi = *(const float4*)x_t[1][d];
            p0 = fmaf(lo.x, w, p0); p1 = fmaf(lo.y, w, p1);
            p2 = fmaf(lo.z, w, p2); p3 = fmaf(lo.w, w, p3);
            p4 = fmaf(hi.x, w, p4); p5 = fmaf(hi.y, w, p5);
            p6 = fmaf(hi.z, w, p6); p7 = fmaf(hi.w, w, p7);
        }
        const float bb = b_p1[h];
        const float pv[ROWG] = {p0 + bb, p1 + bb, p2 + bb, p3 + bb,
                                p4 + bb, p5 + bb, p6 + bb, p7 + bb};
        #pragma unroll
        for (int g = 0; g < ROWG; ++g)
            pib_o[(size_t)(row0 + g) * H + h] = f2bu(pv[g]);
    } else {
        const int h = tid - 384;
        float p0 = 0.f, p1 = 0.f, p2 = 0.f, p3 = 0.f, p4 = 0.f, p5 = 0.f, p6 = 0.f, p7 = 0.f;
        for (int d = 0; d < D; ++d) {
            const float w = w_pj[d * H + h];
            const float4 lo = *(const float4*)x_t[0][d];
            const float4 hi = *(const float4*)x_t[1][d];
            p0 = fmaf(lo.x, w, p0); p1 = fmaf(lo.y, w, p1);
            p2 = fmaf(lo.z, w, p2); p3 = fmaf(lo.w, w, p3);
            p4 = fmaf(hi.x, w, p4); p5 = fmaf(hi.y, w, p5);
            p6 = fmaf(hi.z, w, p6); p7 = fmaf(hi.w, w, p7);
        }
        const float pv[ROWG] = {p0, p1, p2, p3, p4, p5, p6, p7};
        #pragma unroll
        for (int g = 0; g < ROWG; ++g)
            pj_o[(size_t)(row0 + g) * H + h] = f2bu(pv[g]);
    }
    __syncthreads();

    if (tid < ROWG * AC) {
        const int g = tid / AC, c = tid % AC;
        float a = b_a2[c];
        for (int d = 0; d < D; ++d) a = fmaf(y[g][d], w_a2[d * AC + c], a);
        out_atom[(row0 + g) * AC + c] = (pad[row0 + g] != 0) ? 0.0f : a;
    }
}

// per-pair inner body (no sd accumulation — bp2 term handled in finalize)
__device__ __forceinline__ void pair_body(
    const float pvx, const float pvy,
    const float* __restrict__ rbf_row, const float4 dk,
    const float pibx, const float piby,
    const float* wprA, const float* wprB, const float2 wp22,
    float& cdx, float& cdy, float& cdz)
{
    float t0a = pibx + pvx, t0b = 0.0f;
    float t1a = piby + pvy, t1b = 0.0f;
    #pragma unroll
    for (int r = 0; r < R; r += 2) {
        const float qa = rbf_row[r];
        const float qb = rbf_row[r + 1];
        t0a = fmaf(qa, wprA[r],     t0a);
        t0b = fmaf(qb, wprA[r + 1], t0b);
        t1a = fmaf(qa, wprB[r],     t1a);
        t1b = fmaf(qb, wprB[r + 1], t1b);
    }
    const float u0 = fast_silu(t0a + t0b);
    const float u1 = fast_silu(t1a + t1b);
    const float part = u0 * wp22.x + u1 * wp22.y;
    cdx = fmaf(part, dk.x, cdx);
    cdy = fmaf(part, dk.y, cdy);
    cdz = fmaf(part, dk.z, cdz);
}

// ---------------- Kernel 2: pair head — SPLIT=4, pipelined 4-wide bf16 pv ----------------
__global__ __launch_bounds__(256) void pair_kernel(
    const float* __restrict__ coords, const int* __restrict__ pad,
    const float* __restrict__ w_pr, const float* __restrict__ w_p2,
    const unsigned short* __restrict__ pj_i, const unsigned short* __restrict__ pib_i,
    const int* __restrict__ jlist_g, const int* __restrict__ M_g,
    float* __restrict__ cd_part)   // [BN][SPLIT][3]
{
    const int row  = blockIdx.x >> 2;
    const int part_id = blockIdx.x & 3;
    const int b = row >> 9;
    const int tid = threadIdx.x;

    if (pad[row] != 0) {
        if (tid == 0) {
            cd_part[(row * SPLIT + part_id) * 3 + 0] = 0.0f;
            cd_part[(row * SPLIT + part_id) * 3 + 1] = 0.0f;
            cd_part[(row * SPLIT + part_id) * 3 + 2] = 0.0f;
        }
        return;
    }

    __shared__ __align__(16) float s_rbf[CHUNK][20];
    __shared__ __align__(16) float4 s_d4[CHUNK];
    __shared__ int   s_jl[CHUNK];
    __shared__ float rw1[4], rw2[4], rw3[4];

    const int wv = tid >> 6, lane = tid & 63;
    const int M = M_g[b];
    const int Mq  = (M + SPLIT - 1) / SPLIT;
    const int kLo = part_id * Mq;
    const int kHi = min(M, kLo + Mq);

    float wprA[R], wprB[R];
    #pragma unroll
    for (int r = 0; r < R; ++r) {
        const float2 wv2 = ((const float2*)(w_pr + r * H))[lane];
        wprA[r] = wv2.x;
        wprB[r] = wv2.y;
    }
    const ushort2 pibu = ((const ushort2*)(pib_i + (size_t)row * H))[lane];
    const float pibx = bf2f(pibu.x), piby = bf2f(pibu.y);
    const float2 wp22 = ((const float2*)w_p2)[lane];
    const float cix = coords[(size_t)row * 3 + 0];
    const float ciy = coords[(size_t)row * 3 + 1];
    const float ciz = coords[(size_t)row * 3 + 2];

    float cdx = 0.0f, cdy = 0.0f, cdz = 0.0f;
    const unsigned short* pjb = pj_i + (size_t)b * NSEQ * H;
    const float gamma = 14.0625f;  // (15/4)^2

    for (int c0 = kLo; c0 < kHi; c0 += CHUNK) {
        const int cn = (kHi - c0 < CHUNK) ? (kHi - c0) : CHUNK;
        __syncthreads();
        if (tid < cn) {
            const int j = jlist_g[b * NSEQ + c0 + tid];
            s_jl[tid] = j;
            const float* cj = coords + (size_t)(b * NSEQ + j) * 3;
            const float dx = cix - cj[0];
            const float dy = ciy - cj[1];
            const float dz = ciz - cj[2];
            const float sq = dx * dx + dy * dy + dz * dz;
            const float dist = sqrtf(fmaxf(sq, 1e-12f));
            s_d4[tid] = make_float4(dx, dy, dz, 0.0f);
            #pragma unroll
            for (int c = 0; c < 4; ++c) {
                float4 q;
                const float t0 = dist - (float)(4.0 * (4 * c + 0) / 15.0);
                const float t1 = dist - (float)(4.0 * (4 * c + 1) / 15.0);
                const float t2 = dist - (float)(4.0 * (4 * c + 2) / 15.0);
                const float t3 = dist - (float)(4.0 * (4 * c + 3) / 15.0);
                q.x = __expf(-gamma * t0 * t0);
                q.y = __expf(-gamma * t1 * t1);
                q.z = __expf(-gamma * t2 * t2);
                q.w = __expf(-gamma * t3 * t3);
                *(float4*)(&s_rbf[tid][4 * c]) = q;
            }
        }
        __syncthreads();

        const int cl = cn - 1;
        int k = wv;
        ushort2 pv0 = ((const ushort2*)(pjb + (size_t)s_jl[min(k,      cl)] * H))[lane];
        ushort2 pv1 = ((const ushort2*)(pjb + (size_t)s_jl[min(k + 4,  cl)] * H))[lane];
        ushort2 pv2 = ((const ushort2*)(pjb + (size_t)s_jl[min(k + 8,  cl)] * H))[lane];
        ushort2 pv3 = ((const ushort2*)(pjb + (size_t)s_jl[min(k + 12, cl)] * H))[lane];
        for (; k < cn; k += 16) {
            const int kn = k + 16;
            const ushort2 nv0 = ((const ushort2*)(pjb + (size_t)s_jl[min(kn,      cl)] * H))[lane];
            const ushort2 nv1 = ((const ushort2*)(pjb + (size_t)s_jl[min(kn + 4,  cl)] * H))[lane];
            const ushort2 nv2 = ((const ushort2*)(pjb + (size_t)s_jl[min(kn + 8,  cl)] * H))[lane];
            const ushort2 nv3 = ((const ushort2*)(pjb + (size_t)s_jl[min(kn + 12, cl)] * H))[lane];

            const int k1 = k + 4, k2 = k + 8, k3 = k + 12;
            pair_body(bf2f(pv0.x), bf2f(pv0.y), s_rbf[k], s_d4[k], pibx, piby,
                      wprA, wprB, wp22, cdx, cdy, cdz);
            if (k1 < cn) pair_body(bf2f(pv1.x), bf2f(pv1.y), s_rbf[k1], s_d4[k1], pibx, piby,
                                   wprA, wprB, wp22, cdx, cdy, cdz);
            if (k2 < cn) pair_body(bf2f(pv2.x), bf2f(pv2.y), s_rbf[k2], s_d4[k2], pibx, piby,
                                   wprA, wprB, wp22, cdx, cdy, cdz);
            if (k3 < cn) pair_body(bf2f(pv3.x), bf2f(pv3.y), s_rbf[k3], s_d4[k3], pibx, piby,
                                   wprA, wprB, wp22, cdx, cdy, cdz);
            pv0 = nv0; pv1 = nv1; pv2 = nv2; pv3 = nv3;
        }
    }
    #pragma unroll
    for (int off = 32; off; off >>= 1) {
        cdx += __shfl_xor(cdx, off);
        cdy += __shfl_xor(cdy, off);
        cdz += __shfl_xor(cdz, off);
    }
    if (lane == 0) { rw1[wv] = cdx; rw2[wv] = cdy; rw3[wv] = cdz; }
    __syncthreads();
    if (tid == 0) {
        cd_part[(row * SPLIT + part_id) * 3 + 0] = rw1[0] + rw1[1] + rw1[2] + rw1[3];
        cd_part[(row * SPLIT + part_id) * 3 + 1] = rw2[0] + rw2[1] + rw2[2] + rw2[3];
        cd_part[(row * SPLIT + part_id) * 3 + 2] = rw3[0] + rw3[1] + rw3[2] + rw3[3];
    }
}

// ---------------- Kernel 3: finalize — adds closed-form bp2 term, CoM, /denom ----------------
__global__ __launch_bounds__(256) void finalize_kernel(
    const float* __restrict__ cd_part, const int* __restrict__ pad,
    const float* __restrict__ coords, const int* __restrict__ M_g,
    const float* __restrict__ csum_g, const float* __restrict__ b_p2,
    float* __restrict__ out_coord)
{
    const int b = blockIdx.x;
    const int tid = threadIdx.x;
    __shared__ float r1[256], r2[256], r3[256];
    const float bp2 = b_p2[0];
    const float Mf  = (float)M_g[b];
    const float csx = csum_g[b * 3 + 0];
    const float csy = csum_g[b * 3 + 1];
    const float csz = csum_g[b * 3 + 2];

    float sx = 0.0f, sy = 0.0f, sz = 0.0f;
    for (int ii = tid; ii < NSEQ; ii += 256) {
        const int row = b * NSEQ + ii;
        if (pad[row] == 0) {
            float cx = bp2 * fmaf(Mf, coords[(size_t)row * 3 + 0], -csx);
            float cy = bp2 * fmaf(Mf, coords[(size_t)row * 3 + 1], -csy);
            float cz = bp2 * fmaf(Mf, coords[(size_t)row * 3 + 2], -csz);
            #pragma unroll
            for (int q = 0; q < SPLIT; ++q) {
                cx += cd_part[(row * SPLIT + q) * 3 + 0];
                cy += cd_part[(row * SPLIT + q) * 3 + 1];
                cz += cd_part[(row * SPLIT + q) * 3 + 2];
            }
            sx += cx; sy += cy; sz += cz;
        }
    }
    r1[tid] = sx; r2[tid] = sy; r3[tid] = sz;
    __syncthreads();
    for (int s = 128; s > 0; s >>= 1) {
        if (tid < s) { r1[tid] += r1[tid + s]; r2[tid] += r2[tid + s]; r3[tid] += r3[tid + s]; }
        __syncthreads();
    }
    const float denom = fmaxf(Mf, 1.0f);
    const float inv_d = 1.0f / denom;
    const float mx = r1[0] * inv_d * inv_d;
    const float my = r2[0] * inv_d * inv_d;
    const float mz = r3[0] * inv_d * inv_d;
    for (int ii = tid; ii < NSEQ; ii += 256) {
        const int row = b * NSEQ + ii;
        if (pad[row] == 0) {
            float cx = bp2 * fmaf(Mf, coords[(size_t)row * 3 + 0], -csx);
            float cy = bp2 * fmaf(Mf, coords[(size_t)row * 3 + 1], -csy);
            float cz = bp2 * fmaf(Mf, coords[(size_t)row * 3 + 2], -csz);
            #pragma unroll
            for (int q = 0; q < SPLIT; ++q) {
                cx += cd_part[(row * SPLIT + q) * 3 + 0];
                cy += cd_part[(row * SPLIT + q) * 3 + 1];
                cz += cd_part[(row * SPLIT + q) * 3 + 2];
            }
            out_coord[row * 3 + 0] = cx * inv_d - mx;
            out_coord[row * 3 + 1] = cy * inv_d - my;
            out_coord[row * 3 + 2] = cz * inv_d - mz;
        } else {
            out_coord[row * 3 + 0] = 0.0f;
            out_coord[row * 3 + 1] = 0.0f;
            out_coord[row * 3 + 2] = 0.0f;
        }
    }
}

extern "C" void kernel_launch(void* const* d_in, const int* in_sizes, int n_in,
                              void* d_out, int out_size, void* d_ws, size_t ws_size,
                              hipStream_t stream) {
    const float* trunk  = (const float*)d_in[0];
    const float* coords = (const float*)d_in[1];
    const int*   pad    = (const int*)d_in[2];
    const float* ln_g   = (const float*)d_in[3];
    const float* ln_b   = (const float*)d_in[4];
    const float* w_a1   = (const float*)d_in[5];
    const float* b_a1   = (const float*)d_in[6];
    const float* w_a2   = (const float*)d_in[7];
    const float* b_a2   = (const float*)d_in[8];
    const float* w_pi   = (const float*)d_in[9];
    const float* w_pj   = (const float*)d_in[10];
    const float* w_pr   = (const float*)d_in[11];
    const float* b_p1   = (const float*)d_in[12];
    const float* w_p2   = (const float*)d_in[13];
    const float* b_p2   = (const float*)d_in[14];

    float* out_atom  = (float*)d_out;                 // f32 [0:10240]
    float* out_coord = out_atom + (size_t)BN * AC;    // f32 [10240:16384]

    // ws: jlist[4*512] M[16] csum[16] | cd_part[BN*SPLIT*3] | pj bf16[BN*H] | pib bf16[BN*H]
    int*   jlist_g = (int*)d_ws;
    int*   M_g     = jlist_g + 4 * NSEQ;
    float* csum_g  = (float*)(M_g + 16);
    float* cd_part = csum_g + 16;
    unsigned short* pj_buf  = (unsigned short*)(cd_part + (size_t)BN * SPLIT * 3);
    unsigned short* pib_buf = pj_buf + (size_t)BN * H;

    batch_kernel<<<4, 256, 0, stream>>>(pad, coords, jlist_g, M_g, csum_g);
    row_kernel<<<BN / ROWG, 512, 0, stream>>>(trunk, pad, ln_g, ln_b, w_a1, b_a1,
                                              w_a2, b_a2, w_pi, w_pj, b_p1,
                                              out_atom, pj_buf, pib_buf);
    pair_kernel<<<BN * SPLIT, 256, 0, stream>>>(coords, pad, w_pr, w_p2,
                                                pj_buf, pib_buf, jlist_g, M_g, cd_part);
    finalize_kernel<<<4, 256, 0, stream>>>(cd_part, pad, coords, M_g, csum_g,
                                           b_p2, out_coord);
}